// Round 6
// baseline (49.500 us; speedup 1.0000x reference)
//
#include <hip/hip_runtime.h>

#define NUM_CLASSES 100
#define QUEUE_SIZE  256
#define FEATURE_DIM 1024
#define BATCH       4096
#define TOTAL_ROWS  (NUM_CLASSES * QUEUE_SIZE)   // 25600
#define EPS         1e-12f

typedef float f32x4 __attribute__((ext_vector_type(4)));

// ---------------------------------------------------------------------------
// Kernel 1: FIFO slot computation -> inverse map.
// rank[b] = #{ b' < b : labels[b'] == labels[b] }  (serial FIFO semantics)
// row[b]  = labels[b]*QUEUE_SIZE + (queue_ptr[labels[b]] + rank[b]) % QUEUE_SIZE
// inv[row] = max b mapping to row (atomicMax == serial last-write-wins).
// inv pre-initialized to -1 via memsetAsync(0xFF).
// ---------------------------------------------------------------------------
__global__ __launch_bounds__(256) void compute_slots_kernel(
    const int* __restrict__ labels,
    const int* __restrict__ queue_ptr,
    int* __restrict__ inv)
{
    __shared__ int hist[NUM_CLASSES];
    __shared__ int s_lab[256];

    const int tid = threadIdx.x;
    const int chunk_start = blockIdx.x * 256;

    for (int i = tid; i < NUM_CLASSES; i += 256) hist[i] = 0;
    __syncthreads();

    for (int j = tid; j < chunk_start; j += 256) {
        atomicAdd(&hist[labels[j]], 1);
    }
    s_lab[tid] = labels[chunk_start + tid];
    __syncthreads();

    const int lab = s_lab[tid];
    int rank = hist[lab];
    for (int j = 0; j < tid; ++j) {
        rank += (s_lab[j] == lab) ? 1 : 0;
    }
    const int slot = (queue_ptr[lab] + rank) & (QUEUE_SIZE - 1);
    const int row  = lab * QUEUE_SIZE + slot;
    atomicMax(&inv[row], chunk_start + tid);
}

// ---------------------------------------------------------------------------
// Kernel 2: fused writer, TWO rows per wave (8 rows / 256-thread block).
// Branchless: both rows' sources selected by sign of inv[row]; sum-of-squares
// reduction computed unconditionally (VALU is idle anyway); scale = 1.0 for
// copy rows. 8 nt loads issued back-to-back (128 B/lane in flight), then
// 8 nt stores. No LDS, no __syncthreads, no divergence.
// ---------------------------------------------------------------------------
__global__ __launch_bounds__(256) void fused_write_kernel(
    const float* __restrict__ queue,
    const float* __restrict__ emb,
    const int* __restrict__ inv,
    float* __restrict__ out)
{
    const int tid  = threadIdx.x;
    const int lane = tid & 63;
    const int wave = tid >> 6;
    const int row0 = blockIdx.x * 8 + wave * 2;
    const int row1 = row0 + 1;
    const long base0 = (long)row0 * FEATURE_DIM;
    const long base1 = (long)row1 * FEATURE_DIM;

    const int b0 = inv[row0];   // wave-uniform
    const int b1 = inv[row1];   // wave-uniform

    const f32x4* s0 = reinterpret_cast<const f32x4*>(
        (b0 < 0) ? (queue + base0) : (emb + (long)b0 * FEATURE_DIM));
    const f32x4* s1 = reinterpret_cast<const f32x4*>(
        (b1 < 0) ? (queue + base1) : (emb + (long)b1 * FEATURE_DIM));

    // 8 independent 16B loads in flight
    f32x4 a0 = __builtin_nontemporal_load(&s0[lane]);
    f32x4 a1 = __builtin_nontemporal_load(&s0[lane + 64]);
    f32x4 a2 = __builtin_nontemporal_load(&s0[lane + 128]);
    f32x4 a3 = __builtin_nontemporal_load(&s0[lane + 192]);
    f32x4 c0 = __builtin_nontemporal_load(&s1[lane]);
    f32x4 c1 = __builtin_nontemporal_load(&s1[lane + 64]);
    f32x4 c2 = __builtin_nontemporal_load(&s1[lane + 128]);
    f32x4 c3 = __builtin_nontemporal_load(&s1[lane + 192]);

    // unconditional reductions (cheap; removes divergence)
    float ssa = a0.x*a0.x + a0.y*a0.y + a0.z*a0.z + a0.w*a0.w
              + a1.x*a1.x + a1.y*a1.y + a1.z*a1.z + a1.w*a1.w
              + a2.x*a2.x + a2.y*a2.y + a2.z*a2.z + a2.w*a2.w
              + a3.x*a3.x + a3.y*a3.y + a3.z*a3.z + a3.w*a3.w;
    float ssc = c0.x*c0.x + c0.y*c0.y + c0.z*c0.z + c0.w*c0.w
              + c1.x*c1.x + c1.y*c1.y + c1.z*c1.z + c1.w*c1.w
              + c2.x*c2.x + c2.y*c2.y + c2.z*c2.z + c2.w*c2.w
              + c3.x*c3.x + c3.y*c3.y + c3.z*c3.z + c3.w*c3.w;
    #pragma unroll
    for (int off = 32; off; off >>= 1) {
        ssa += __shfl_xor(ssa, off, 64);
        ssc += __shfl_xor(ssc, off, 64);
    }
    const float sc0 = (b0 < 0) ? 1.0f : 1.0f / fmaxf(sqrtf(ssa), EPS);
    const float sc1 = (b1 < 0) ? 1.0f : 1.0f / fmaxf(sqrtf(ssc), EPS);

    f32x4* d0 = reinterpret_cast<f32x4*>(out + base0);
    f32x4* d1 = reinterpret_cast<f32x4*>(out + base1);
    __builtin_nontemporal_store(a0 * sc0, &d0[lane]);
    __builtin_nontemporal_store(a1 * sc0, &d0[lane + 64]);
    __builtin_nontemporal_store(a2 * sc0, &d0[lane + 128]);
    __builtin_nontemporal_store(a3 * sc0, &d0[lane + 192]);
    __builtin_nontemporal_store(c0 * sc1, &d1[lane]);
    __builtin_nontemporal_store(c1 * sc1, &d1[lane + 64]);
    __builtin_nontemporal_store(c2 * sc1, &d1[lane + 128]);
    __builtin_nontemporal_store(c3 * sc1, &d1[lane + 192]);
}

// ---------------------------------------------------------------------------
extern "C" void kernel_launch(void* const* d_in, const int* in_sizes, int n_in,
                              void* d_out, int out_size, void* d_ws, size_t ws_size,
                              hipStream_t stream)
{
    const float* embeddings = (const float*)d_in[0];   // (4096, 1024) f32
    const int*   labels     = (const int*)d_in[1];     // (4096,) int
    const float* queue      = (const float*)d_in[2];   // (100, 256, 1024) f32
    const int*   queue_ptr  = (const int*)d_in[3];     // (100,) int

    float* out = (float*)d_out;                        // (100, 256, 1024) f32
    int*   inv = (int*)d_ws;                           // 25600 ints scratch

    // 0) inv = -1
    (void)hipMemsetAsync(inv, 0xFF, TOTAL_ROWS * sizeof(int), stream);

    // 1) FIFO slots + inverse map (16 blocks x 256 threads)
    compute_slots_kernel<<<BATCH / 256, 256, 0, stream>>>(labels, queue_ptr, inv);

    // 2) fused copy/normalize-scatter: 2 rows per wave, 8 rows per block
    fused_write_kernel<<<TOTAL_ROWS / 8, 256, 0, stream>>>(
        queue, embeddings, inv, out);
}